// Round 13
// baseline (669.888 us; speedup 1.0000x reference)
//
#include <hip/hip_runtime.h>
#include <math.h>

#define BATCH 64
#define CC    256
#define ATTRN 300
#define DD    256
#define HW    784
#define HW4   196   // HW / 4
#define O1    32
#define TF4   49    // float4 columns per tile (4 tiles * 49 * 4 = 784)

// ws layout (floats):
// [16384, 540672)         : corrT [64][256 t][32 o]
// [540672, 540672+6422528): part [b][tile][cg][o][196]  (cg = z*2+ci)
#define PART_OFF 540672

// ---------------------------------------------------------------- k2 (fused k1+sketch+circulant)
__global__ __launch_bounds__(512) void k2_fused(
    const float* __restrict__ attr_one_hot,
    const float* __restrict__ W_emb,
    const float* __restrict__ b_emb,
    const int*   __restrict__ h1,
    const float* __restrict__ s1,
    const float* __restrict__ conv1_w,
    float* __restrict__ corrT)
{
    const int b = blockIdx.x, og = blockIdx.y;
    const int tid = threadIdx.x;
    const int t = tid & 255, kh = tid >> 8;   // kh is wave-uniform
    const int o0 = og * 8;

    __shared__ float s_attr[ATTRN];
    __shared__ float s_sx[DD];
    __shared__ float s_w1[8][DD];
    __shared__ float s_part[8][DD];

    if (kh == 0) {
        s_sx[t] = 0.f;
        if (t < 75) {
            float4 a = *(const float4*)(attr_one_hot + b * ATTRN + 4 * t);
            *(float4*)&s_attr[4 * t] = a;
        }
    } else {
#pragma unroll
        for (int j = 0; j < 8; ++j) s_w1[j][t] = conv1_w[(o0 + j) * CC + t];
    }
    __syncthreads();

    if (kh == 0) {
        float acc = b_emb[t];
        const float* wr = W_emb + (size_t)t * ATTRN;
#pragma unroll 5
        for (int v = 0; v < 75; ++v) {
            float4 w = *(const float4*)(wr + 4 * v);
            float4 a = *(const float4*)(&s_attr[4 * v]);
            acc += w.x * a.x + w.y * a.y + w.z * a.z + w.w * a.w;
        }
        atomicAdd(&s_sx[h1[t]], s1[t] * acc);
    }
    __syncthreads();

    float acc[8] = {0.f,0.f,0.f,0.f,0.f,0.f,0.f,0.f};
    const int kbase = kh << 7;
    for (int k4 = 0; k4 < 32; ++k4) {
        const int k = kbase + 4 * k4;
        float x0 = s_sx[(k     - t) & 255];
        float x1 = s_sx[(k + 1 - t) & 255];
        float x2 = s_sx[(k + 2 - t) & 255];
        float x3 = s_sx[(k + 3 - t) & 255];
#pragma unroll
        for (int oo = 0; oo < 8; ++oo) {
            float4 w = *(const float4*)&s_w1[oo][k];
            acc[oo] += w.x * x0 + w.y * x1 + w.z * x2 + w.w * x3;
        }
    }
    if (kh == 1) {
#pragma unroll
        for (int oo = 0; oo < 8; ++oo) s_part[oo][t] = acc[oo];
    }
    __syncthreads();
    if (kh == 0) {
        float4 r0, r1;
        r0.x = acc[0] + s_part[0][t]; r0.y = acc[1] + s_part[1][t];
        r0.z = acc[2] + s_part[2][t]; r0.w = acc[3] + s_part[3][t];
        r1.x = acc[4] + s_part[4][t]; r1.y = acc[5] + s_part[5][t];
        r1.z = acc[6] + s_part[6][t]; r1.w = acc[7] + s_part[7][t];
        float4* dst = (float4*)(corrT + ((size_t)b * DD + t) * O1 + o0);
        dst[0] = r0; dst[1] = r1;
    }
}

// ---------------------------------------------------------------- k3a
// Partial GEMM, 512 threads = 8 waves = 2 ci x 4 oi (per-wave code
// byte-identical to the clean-compiling r8/r9 monolith). Grid (64,4,2):
// block covers 128 channels [128z, 128z+128). LDS = 18,432 + 49,152 =
// 67,584B -> 2 blocks/CU co-resident (the phase-overlap the 1-block/CU
// monolith lacked). launch_bounds(512,1): the only bounds family that
// never spilled (r8/r9 VGPR 56/44 vs r11 (,4)=64+spill, r12 ()=256+spill).
// Each wave stores its 64-ch partial acc; cg = z*2+ci reproduces the
// monolith's four ci partials exactly (k3b sums in the old order).
#define FMA4(A, S, E) { (A).x += (S)*(E).x; (A).y += (S)*(E).y; (A).z += (S)*(E).z; (A).w += (S)*(E).w; }

#define PL_OFF 0        // Pl[c_local][j] = lds[c_local*36 + j], 4608 floats
#define ST_OFF 4608     // stage[ci][buf3][row8][256]: ci*6144 + buf*2048 + row*256

__device__ __forceinline__ void gld_lds16(const float4* g, float* l) {
    __builtin_amdgcn_global_load_lds(
        (__attribute__((address_space(1))) void*)g,
        (__attribute__((address_space(3))) void*)l,
        16, 0, 0);
}

__global__ __launch_bounds__(512, 1) void k3a_gemm(
    const float* __restrict__ ent,
    const float* __restrict__ corrT,
    const int*   __restrict__ h2,
    const float* __restrict__ s2,
    float* __restrict__ part)
{
    extern __shared__ float lds[];
    const int b = blockIdx.x, tile = blockIdx.y, z = blockIdx.z;
    const int tid  = threadIdx.x;
    const int wv   = tid >> 6, lane = tid & 63;
    const int ci   = wv >> 2;     // c-sub: c in [128z+64ci, 128z+64ci+64)
    const int oi   = wv & 3;      // o-octet

    const bool act = lane < TF4;
    const int lclamp = act ? lane : (TF4 - 1);
    const float4* ent4 = (const float4*)ent;
    const int c0 = z * 128 + ci * 64;
    const float4* gbase = ent4 + (size_t)(b * CC + c0) * HW4 + tile * TF4 + lclamp;
    const int rr0 = 2 * oi;                       // this wave's 2 staged rows
    float* const stbase = &lds[ST_OFF + ci * 6144 + rr0 * 256];

    // ---- prologue: issue chunk 0 stage, then Pl gather, then full drain
    gld_lds16(gbase + (size_t)(rr0)     * HW4, stbase);          // buf 0
    gld_lds16(gbase + (size_t)(rr0 + 1) * HW4, stbase + 256);

    {
        const int cl = tid >> 2, qp = tid & 3;    // c_local in [0,128), f4-pair
        const int hc = h2[z * 128 + cl];
        const float sc = s2[z * 128 + cl];
        const float4* src = (const float4*)(corrT + ((size_t)b * DD + hc) * O1);
        float4 x0 = src[2 * qp], x1 = src[2 * qp + 1];
        x0.x *= sc; x0.y *= sc; x0.z *= sc; x0.w *= sc;
        x1.x *= sc; x1.y *= sc; x1.z *= sc; x1.w *= sc;
        *(float4*)&lds[PL_OFF + cl * 36 + 8 * qp]     = x0;
        *(float4*)&lds[PL_OFF + cl * 36 + 8 * qp + 4] = x1;
    }
    __syncthreads();   // vmcnt(0): chunk 0 + gather drained; Pl visible

    gld_lds16(gbase + (size_t)(8 + rr0)     * HW4, stbase + 2048);   // chunk 1
    gld_lds16(gbase + (size_t)(8 + rr0 + 1) * HW4, stbase + 2048 + 256);

    float4 acc[8];
#pragma unroll
    for (int o = 0; o < 8; ++o) acc[o] = make_float4(0.f, 0.f, 0.f, 0.f);

    const int clb = ci * 64;    // c_local base for this wave within Pl
#pragma unroll
    for (int k = 0; k < 8; ++k) {
        if (k < 6) {   // chunk k+2 into buf (k+2)%3 (sealed at barrier k-1)
            float* d = &lds[ST_OFF + ci * 6144 + ((k + 2) % 3) * 2048 + rr0 * 256];
            gld_lds16(gbase + (size_t)((k + 2) * 8 + rr0)     * HW4, d);
            gld_lds16(gbase + (size_t)((k + 2) * 8 + rr0 + 1) * HW4, d + 256);
        }
        const float* sb = &lds[ST_OFF + ci * 6144 + (k % 3) * 2048 + 4 * lane];
#pragma unroll
        for (int cc = 0; cc < 8; ++cc) {
            const int cl = clb + k * 8 + cc;
            float4 e4 = *(const float4*)(sb + cc * 256);
            float4 pa = *(const float4*)&lds[PL_OFF + cl * 36 + 8 * oi];
            float4 pb = *(const float4*)&lds[PL_OFF + cl * 36 + 8 * oi + 4];
            FMA4(acc[0], pa.x, e4); FMA4(acc[1], pa.y, e4);
            FMA4(acc[2], pa.z, e4); FMA4(acc[3], pa.w, e4);
            FMA4(acc[4], pb.x, e4); FMA4(acc[5], pb.y, e4);
            FMA4(acc[6], pb.z, e4); FMA4(acc[7], pb.w, e4);
        }
        if (k < 6) {
            asm volatile("s_waitcnt vmcnt(2)" ::: "memory");
            __builtin_amdgcn_s_barrier();
        } else if (k == 6) {
            asm volatile("s_waitcnt vmcnt(0)" ::: "memory");
            __builtin_amdgcn_s_barrier();
        }
    }

    // ---- store partials: cg = z*2+ci; row = ((b*4+tile)*4+cg)*32 + o
    if (act) {
        const int cg = z * 2 + ci;
        float* prow = part + ((size_t)((b * 4 + tile) * 4 + cg) * O1 + 8 * oi) * HW4 + 4 * lane;
#pragma unroll
        for (int i = 0; i < 8; ++i)
            *(float4*)(prow + (size_t)i * HW4) = acc[i];
    }
}

// ---------------------------------------------------------------- k3b
// Combine partials (exact old assoc order), relu+conv2+sigmoid, output.
__global__ __launch_bounds__(1024, 1) void k3b_out(
    const float* __restrict__ ent,
    const float* __restrict__ part,
    const float* __restrict__ conv2_w,
    float* __restrict__ out_map,
    float* __restrict__ out_feat)
{
    const int b = blockIdx.x, tile = blockIdx.y;
    const int tid = threadIdx.x;
    const int wv  = tid >> 6, lane = tid & 63;

    __shared__ float  v_lds[O1][HW4];
    __shared__ float4 s_amap4[TF4];
    __shared__ float  s_c2[O1];

    if (tid < O1) s_c2[tid] = conv2_w[tid];

    // ---- phase 1: v[o][r] = ((p0+p1)+p2)+p3 (same assoc order as old reduce)
    const float* pb0 = part + (size_t)(b * 4 + tile) * 4 * O1 * HW4;  // cg stride O1*HW4
    if (tid < 4 * HW4) {
        const int og = tid / HW4, r = tid - og * HW4;   // og in [0,4): 8 o's each
#pragma unroll
        for (int i = 0; i < 8; ++i) {
            const int o = og * 8 + i;
            float v0 = pb0[(size_t)(0 * O1 + o) * HW4 + r];
            float v1 = pb0[(size_t)(1 * O1 + o) * HW4 + r];
            float v2 = pb0[(size_t)(2 * O1 + o) * HW4 + r];
            float v3 = pb0[(size_t)(3 * O1 + o) * HW4 + r];
            v_lds[o][r] = ((v0 + v1) + v2) + v3;
        }
    }
    __syncthreads();

    // ---- phase 2: pre = sum_o c2[o]*relu(v) in strict o-ascending order
    if (tid < HW4) {
        float pre = 0.f;
#pragma unroll
        for (int o = 0; o < O1; ++o) pre += s_c2[o] * fmaxf(v_lds[o][tid], 0.f);
        float am = 1.f / (1.f + expf(-pre));
        ((float*)&s_amap4[tid >> 2])[tid & 3] = am;
        out_map[b * HW + tile * (4 * TF4) + tid] = am;
    }
    __syncthreads();

    // ---- output stream: wave wv covers c in [16*wv, 16*wv+16), lanes=cols
    const bool act = lane < TF4;
    const int f4i = tile * TF4 + (act ? lane : 0);
    const float4 am4 = s_amap4[act ? lane : 0];
    const float4* ent4 = (const float4*)ent;
    float4* of4 = (float4*)out_feat;
    const int cb = wv * 16;
#pragma unroll 4
    for (int cc = 0; cc < 16; ++cc) {
        const int c = cb + cc;
        if (act) {
            const size_t idx = (size_t)(b * CC + c) * HW4 + f4i;
            float4 e4 = ent4[idx];
            float4 r;
            r.x = am4.x * e4.x; r.y = am4.y * e4.y;
            r.z = am4.z * e4.z; r.w = am4.w * e4.w;
            of4[idx] = r;
        }
    }
}

extern "C" void kernel_launch(void* const* d_in, const int* in_sizes, int n_in,
                              void* d_out, int out_size, void* d_ws, size_t ws_size,
                              hipStream_t stream) {
    const float* ent   = (const float*)d_in[0];
    const float* attr  = (const float*)d_in[1];
    const float* W_emb = (const float*)d_in[2];
    const float* b_emb = (const float*)d_in[3];
    const int*   h1    = (const int*)d_in[4];
    const float* s1    = (const float*)d_in[5];
    const int*   h2    = (const int*)d_in[6];
    const float* s2    = (const float*)d_in[7];
    const float* c1w   = (const float*)d_in[8];
    const float* c2w   = (const float*)d_in[9];

    float* ws    = (float*)d_ws;
    float* corrT = ws + 16384;
    float* part  = ws + PART_OFF;

    float* out      = (float*)d_out;
    float* out_map  = out;                 // [64,1,28,28]
    float* out_feat = out + BATCH * HW;    // [64,256,28,28]

    hipLaunchKernelGGL(k2_fused, dim3(BATCH, 4), dim3(512), 0, stream,
                       attr, W_emb, b_emb, h1, s1, c1w, corrT);
    hipLaunchKernelGGL(k3a_gemm, dim3(BATCH, 4, 2), dim3(512),
                       (4608 + 12288) * sizeof(float), stream,
                       ent, corrT, h2, s2, part);
    hipLaunchKernelGGL(k3b_out, dim3(BATCH, 4), dim3(1024), 0, stream,
                       ent, part, c2w, out_map, out_feat);
}

// Round 14
// 148.748 us; speedup vs baseline: 4.5035x; 4.5035x over previous
//
#include <hip/hip_runtime.h>
#include <math.h>

#define BATCH 64
#define CC    256
#define ATTRN 300
#define DD    256
#define HW    784
#define HW4   196   // HW / 4
#define O1    32
#define TF4   49    // float4 columns per tile (4 tiles * 49 * 4 = 784)

// ws layout (floats):
// [16384, 540672)  : corrT [64][256 t][32 o]   (t-major, o contiguous)

// ---------------------------------------------------------------- k2 (fused k1+sketch+circulant)
__global__ __launch_bounds__(512) void k2_fused(
    const float* __restrict__ attr_one_hot,
    const float* __restrict__ W_emb,
    const float* __restrict__ b_emb,
    const int*   __restrict__ h1,
    const float* __restrict__ s1,
    const float* __restrict__ conv1_w,
    float* __restrict__ corrT)
{
    const int b = blockIdx.x, og = blockIdx.y;
    const int tid = threadIdx.x;
    const int t = tid & 255, kh = tid >> 8;   // kh is wave-uniform
    const int o0 = og * 8;

    __shared__ float s_attr[ATTRN];
    __shared__ float s_sx[DD];
    __shared__ float s_w1[8][DD];
    __shared__ float s_part[8][DD];

    if (kh == 0) {
        s_sx[t] = 0.f;
        if (t < 75) {
            float4 a = *(const float4*)(attr_one_hot + b * ATTRN + 4 * t);
            *(float4*)&s_attr[4 * t] = a;
        }
    } else {
#pragma unroll
        for (int j = 0; j < 8; ++j) s_w1[j][t] = conv1_w[(o0 + j) * CC + t];
    }
    __syncthreads();

    if (kh == 0) {
        float acc = b_emb[t];
        const float* wr = W_emb + (size_t)t * ATTRN;   // rows are 1200B = 16B-aligned
#pragma unroll 5
        for (int v = 0; v < 75; ++v) {
            float4 w = *(const float4*)(wr + 4 * v);
            float4 a = *(const float4*)(&s_attr[4 * v]);
            acc += w.x * a.x + w.y * a.y + w.z * a.z + w.w * a.w;
        }
        atomicAdd(&s_sx[h1[t]], s1[t] * acc);
    }
    __syncthreads();

    float acc[8] = {0.f,0.f,0.f,0.f,0.f,0.f,0.f,0.f};
    const int kbase = kh << 7;
    for (int k4 = 0; k4 < 32; ++k4) {
        const int k = kbase + 4 * k4;
        float x0 = s_sx[(k     - t) & 255];
        float x1 = s_sx[(k + 1 - t) & 255];
        float x2 = s_sx[(k + 2 - t) & 255];
        float x3 = s_sx[(k + 3 - t) & 255];
#pragma unroll
        for (int oo = 0; oo < 8; ++oo) {
            float4 w = *(const float4*)&s_w1[oo][k];
            acc[oo] += w.x * x0 + w.y * x1 + w.z * x2 + w.w * x3;
        }
    }
    if (kh == 1) {
#pragma unroll
        for (int oo = 0; oo < 8; ++oo) s_part[oo][t] = acc[oo];
    }
    __syncthreads();
    if (kh == 0) {
        float4 r0, r1;
        r0.x = acc[0] + s_part[0][t]; r0.y = acc[1] + s_part[1][t];
        r0.z = acc[2] + s_part[2][t]; r0.w = acc[3] + s_part[3][t];
        r1.x = acc[4] + s_part[4][t]; r1.y = acc[5] + s_part[5][t];
        r1.z = acc[6] + s_part[6][t]; r1.w = acc[7] + s_part[7][t];
        float4* dst = (float4*)(corrT + ((size_t)b * DD + t) * O1 + o0);
        dst[0] = r0; dst[1] = r1;
    }
}

// ---------------------------------------------------------------- k3
// PROVEN BEST (r9: 41.9us, VGPR 44, no scratch). 16 waves = 4 ci x 4 oi.
// ent staged to LDS via global_load_lds, 3-buffer counted-vmcnt pipeline.
// DO NOT split this kernel or shrink the block: the same inner loop in a
// 256/512-thread partial-store kernel triggers pathological scratch
// placement under every launch_bounds tried (r11: 1.0GB, r12: 0.5GB,
// r13: 1.6GB scratch traffic). Only this 1024-thread monolith with the
// acc->LDS reduce epilogue compiles clean (r8/r9).
#define FMA4(A, S, E) { (A).x += (S)*(E).x; (A).y += (S)*(E).y; (A).z += (S)*(E).z; (A).w += (S)*(E).w; }

#define PL_OFF 0        // Pl[c][j] = lds[c*36 + j], 9216 floats
#define ST_OFF 9216     // stage[ci][buf3][row8][256]: ci*6144 + buf*2048 + row*256

__device__ __forceinline__ void gld_lds16(const float4* g, float* l) {
    __builtin_amdgcn_global_load_lds(
        (__attribute__((address_space(1))) void*)g,
        (__attribute__((address_space(3))) void*)l,
        16, 0, 0);
}

__global__ __launch_bounds__(1024, 1) void k3_main(
    const float* __restrict__ ent,
    const float* __restrict__ corrT,
    const int*   __restrict__ h2,
    const float* __restrict__ s2,
    const float* __restrict__ conv2_w,
    float* __restrict__ out_map,
    float* __restrict__ out_feat)
{
    extern __shared__ float lds[];
    const int b = blockIdx.x, tile = blockIdx.y;
    const int tid  = threadIdx.x;
    const int wv   = tid >> 6, lane = tid & 63;
    const int ci   = wv >> 2;     // c-split: c in [64*ci, 64*ci+64)
    const int oi   = wv & 3;      // o-octet: o in [8*oi, 8*oi+8)

    __shared__ float4 s_amap4[TF4];
    __shared__ float  s_c2[O1];

    const bool act = lane < TF4;
    const int lclamp = act ? lane : (TF4 - 1);
    const int f4i = tile * TF4 + lclamp;
    const float4* ent4 = (const float4*)ent;
    const int c0 = ci * 64;
    const float4* gbase = ent4 + (size_t)(b * CC + c0) * HW4 + tile * TF4 + lclamp;
    const int rr0 = 2 * oi;                      // this wave's 2 staged rows
    float* const stbase = &lds[ST_OFF + ci * 6144 + rr0 * 256];

    // ---- prologue: issue chunk 0, then Pl staging, then full drain
    gld_lds16(gbase + (size_t)(rr0)     * HW4, stbase);          // buf 0
    gld_lds16(gbase + (size_t)(rr0 + 1) * HW4, stbase + 256);

    {
        const int c = tid >> 2, qp = tid & 3;
        const int hc = h2[c];
        const float sc = s2[c];
        const float4* src = (const float4*)(corrT + ((size_t)b * DD + hc) * O1);
        float4 x0 = src[2 * qp], x1 = src[2 * qp + 1];
        x0.x *= sc; x0.y *= sc; x0.z *= sc; x0.w *= sc;
        x1.x *= sc; x1.y *= sc; x1.z *= sc; x1.w *= sc;
        *(float4*)&lds[PL_OFF + c * 36 + 8 * qp]     = x0;
        *(float4*)&lds[PL_OFF + c * 36 + 8 * qp + 4] = x1;
        if (tid < O1) s_c2[tid] = conv2_w[tid];
    }
    __syncthreads();   // vmcnt(0): chunk 0 + all prologue loads drained; Pl visible

    // issue chunk 1 (buf 1) — the only outstanding vmem from here on
    gld_lds16(gbase + (size_t)(8 + rr0)     * HW4, stbase + 2048);
    gld_lds16(gbase + (size_t)(8 + rr0 + 1) * HW4, stbase + 2048 + 256);

    float4 acc[8];
#pragma unroll
    for (int o = 0; o < 8; ++o) acc[o] = make_float4(0.f, 0.f, 0.f, 0.f);

    // ---- GEMM: 8 chunks of 8 channels, 3-buffer counted-vmcnt pipeline
#pragma unroll
    for (int k = 0; k < 8; ++k) {
        if (k < 6) {   // issue chunk k+2 into buf (k+2)%3 (sealed at barrier k-1)
            float* d = stbase + ((k + 2) % 3) * 2048;
            gld_lds16(gbase + (size_t)((k + 2) * 8 + rr0)     * HW4, d);
            gld_lds16(gbase + (size_t)((k + 2) * 8 + rr0 + 1) * HW4, d + 256);
        }
        const float* sb = &lds[ST_OFF + ci * 6144 + (k % 3) * 2048 + 4 * lane];
#pragma unroll
        for (int cc = 0; cc < 8; ++cc) {
            const int c = c0 + k * 8 + cc;
            float4 e4 = *(const float4*)(sb + cc * 256);
            float4 pa = *(const float4*)&lds[PL_OFF + c * 36 + 8 * oi];
            float4 pb = *(const float4*)&lds[PL_OFF + c * 36 + 8 * oi + 4];
            FMA4(acc[0], pa.x, e4); FMA4(acc[1], pa.y, e4);
            FMA4(acc[2], pa.z, e4); FMA4(acc[3], pa.w, e4);
            FMA4(acc[4], pb.x, e4); FMA4(acc[5], pb.y, e4);
            FMA4(acc[6], pb.z, e4); FMA4(acc[7], pb.w, e4);
        }
        if (k < 6) {
            asm volatile("s_waitcnt vmcnt(2)" ::: "memory");   // chunk k+1 landed
            __builtin_amdgcn_s_barrier();
        } else if (k == 6) {
            asm volatile("s_waitcnt vmcnt(0)" ::: "memory");   // chunk 7 landed
            __builtin_amdgcn_s_barrier();
        }
        // k==7: reduce loop's first __syncthreads provides the barrier
    }

    // ---- cross-wave reduce + relu + conv2, one o-octet per pass
    // red[4][TF4][9] float4 aliases the (dead) stage region
    float4* red = (float4*)&lds[ST_OFF];
    float pre = 0.f;
#pragma unroll
    for (int g = 0; g < 4; ++g) {
        __syncthreads();
        if (oi == g && act) {
#pragma unroll
            for (int i = 0; i < 8; ++i) red[(ci * TF4 + lane) * 9 + i] = acc[i];
        }
        __syncthreads();
        if (tid < 4 * TF4) {
            const int fi = tid >> 2, j = tid & 3;
#pragma unroll
            for (int i = 0; i < 8; ++i) {
                float v = ((const float*)&red[(0 * TF4 + fi) * 9 + i])[j]
                        + ((const float*)&red[(1 * TF4 + fi) * 9 + i])[j]
                        + ((const float*)&red[(2 * TF4 + fi) * 9 + i])[j]
                        + ((const float*)&red[(3 * TF4 + fi) * 9 + i])[j];
                pre += s_c2[8 * g + i] * fmaxf(v, 0.f);
            }
        }
    }
    __syncthreads();
    if (tid < 4 * TF4) {
        const int fi = tid >> 2, j = tid & 3;
        float am = 1.f / (1.f + expf(-pre));
        ((float*)&s_amap4[fi])[j] = am;
        out_map[b * HW + tile * (4 * TF4) + tid] = am;
    }
    __syncthreads();

    // ---- output pass: wave wv covers c in [16*wv, 16*wv+16) — L2/L3-warm
    const float4 am4 = s_amap4[act ? lane : 0];
    float4* of4 = (float4*)out_feat;
    const int cb = wv * 16;
#pragma unroll 4
    for (int cc = 0; cc < 16; ++cc) {
        const int c = cb + cc;
        if (act) {
            const size_t idx = (size_t)(b * CC + c) * HW4 + f4i;
            float4 e4 = ent4[idx];
            float4 r;
            r.x = am4.x * e4.x; r.y = am4.y * e4.y;
            r.z = am4.z * e4.z; r.w = am4.w * e4.w;
            of4[idx] = r;
        }
    }
}

extern "C" void kernel_launch(void* const* d_in, const int* in_sizes, int n_in,
                              void* d_out, int out_size, void* d_ws, size_t ws_size,
                              hipStream_t stream) {
    const float* ent   = (const float*)d_in[0];
    const float* attr  = (const float*)d_in[1];
    const float* W_emb = (const float*)d_in[2];
    const float* b_emb = (const float*)d_in[3];
    const int*   h1    = (const int*)d_in[4];
    const float* s1    = (const float*)d_in[5];
    const int*   h2    = (const int*)d_in[6];
    const float* s2    = (const float*)d_in[7];
    const float* c1w   = (const float*)d_in[8];
    const float* c2w   = (const float*)d_in[9];

    float* ws    = (float*)d_ws;
    float* corrT = ws + 16384;

    float* out      = (float*)d_out;
    float* out_map  = out;                 // [64,1,28,28]
    float* out_feat = out + BATCH * HW;    // [64,256,28,28]

    hipLaunchKernelGGL(k2_fused, dim3(BATCH, 4), dim3(512), 0, stream,
                       attr, W_emb, b_emb, h1, s1, c1w, corrT);
    hipLaunchKernelGGL(k3_main, dim3(BATCH, 4), dim3(1024),
                       (9216 + 24576) * sizeof(float), stream,
                       ent, corrT, h2, s2, c2w, out_map, out_feat);
}